// Round 12
// baseline (109.992 us; speedup 1.0000x reference)
//
#include <hip/hip_runtime.h>
#include <math.h>

typedef _Float16 v8h __attribute__((ext_vector_type(8)));
typedef float v4f __attribute__((ext_vector_type(4)));
typedef float v16f __attribute__((ext_vector_type(16)));

#define MFMA32(a, b, c) __builtin_amdgcn_mfma_f32_32x32x16_f16((a), (b), (c), 0, 0, 0)
#define MFMA16(a, b, c) __builtin_amdgcn_mfma_f32_16x16x32_f16((a), (b), (c), 0, 0, 0)
#define ZV4 ((v4f){0.f, 0.f, 0.f, 0.f})
#define LOG2E 1.44269504f

// swizzled tile addressing (byte offsets)
#define TA64(row, colb)  ((((row) * 128) + (colb)) ^ (((row) & 7) << 4))
#define TA128(row, colb) ((((row) * 256) + (colb)) ^ (((row) & 15) << 4))

__device__ __forceinline__ unsigned int pk_f16(float a, float b) {
    return __builtin_bit_cast(unsigned int, __builtin_amdgcn_cvt_pkrtz(a, b));
}
__device__ __forceinline__ void pl32swap(unsigned int& a, unsigned int& b) {
    asm("v_permlane32_swap_b32 %0, %1" : "+v"(a), "+v"(b));
}

// ---------------------------------------------------------------- k_prep ----
__global__ __launch_bounds__(256) void k_prep(
    const float* __restrict__ tw, const float* __restrict__ pw,
    const float* __restrict__ gw,
    const float* __restrict__ Ww, const float* __restrict__ Wb,
    const float* __restrict__ gamma, const float* __restrict__ beta,
    const float* __restrict__ mean, const float* __restrict__ var,
    _Float16* __restrict__ Wt, _Float16* __restrict__ wallT,
    float* __restrict__ sc, float* __restrict__ bi)
{
    int gid = blockIdx.x * 256 + threadIdx.x;    // 4096 threads
    #pragma unroll
    for (int r = 0; r < 2; ++r) {
        int idx = r * 4096 + gid;                // 8192 = 64*128
        int d = idx >> 7, c = idx & 127;
        Wt[c * 64 + d] = (_Float16)Ww[idx];      // Wt[c][d] = W_w[d][c]
    }
    #pragma unroll
    for (int r = 0; r < 6; ++r) {
        int idx = r * 4096 + gid;                // 24576 = 3*64*128
        int p = idx >> 13, rem = idx & 8191;
        int o = rem >> 7, k = rem & 127;
        const float* wm = (p == 0) ? tw : (p == 1) ? pw : gw;
        wallT[idx] = (_Float16)wm[k * 64 + o];
    }
    if (blockIdx.x == 0 && threadIdx.x < 128) {
        int c = threadIdx.x;
        float inv = gamma[c] * rsqrtf(var[c] + 1e-4f);
        sc[c] = inv;
        bi[c] = (Wb[c] - mean[c]) * inv + beta[c];
    }
}

// ---------------------------------------------------------------- k_proj ----
// fp16 MFMA projections, no barriers. theta is PRE-SCALED by log2(e) so the
// attention softmax can use exp2 directly (saves a v_mul per score).
__global__ __launch_bounds__(512, 4) void k_proj(
    const float* __restrict__ x, const _Float16* __restrict__ wallT,
    const float* __restrict__ tb, const float* __restrict__ pb,
    const float* __restrict__ gb,
    _Float16* __restrict__ theta, _Float16* __restrict__ phi,
    _Float16* __restrict__ gT)
{
    __shared__ __align__(16) _Float16 tsc[8][16 * 72];
    const int t = threadIdx.x;
    const int w = t >> 6, l = t & 63, h = l >> 4, lo = l & 15;
    const int tok0 = blockIdx.x * 128 + w * 16;
    _Float16* tw_l = &tsc[w][0];

    v8h xA[4];
    #pragma unroll
    for (int kc = 0; kc < 4; ++kc) {
        const float* px = x + (size_t)(tok0 + lo) * 128 + kc * 32 + h * 8;
        float4 f0 = *(const float4*)(px);
        float4 f1 = *(const float4*)(px + 4);
        uint4 u;
        u.x = pk_f16(f0.x, f0.y); u.y = pk_f16(f0.z, f0.w);
        u.z = pk_f16(f1.x, f1.y); u.w = pk_f16(f1.z, f1.w);
        xA[kc] = __builtin_bit_cast(v8h, u);
    }

    #pragma unroll
    for (int p = 0; p < 2; ++p) {                // theta, phi
        const _Float16* wp = wallT + p * 8192;
        const float* bias = (p == 0) ? tb : pb;
        _Float16* dst = (p == 0) ? theta : phi;
        const float scale = (p == 0) ? LOG2E : 1.0f;
        #pragma unroll
        for (int oc = 0; oc < 4; ++oc) {
            int o = oc * 16 + lo;
            v4f acc = ZV4;
            #pragma unroll
            for (int kc = 0; kc < 4; ++kc) {
                v8h B = *(const v8h*)(wp + o * 128 + kc * 32 + h * 8);
                acc = MFMA16(xA[kc], B, acc);
            }
            float bv = bias[o];
            #pragma unroll
            for (int rr = 0; rr < 4; ++rr)
                tw_l[(4 * h + rr) * 72 + o] = (_Float16)((acc[rr] + bv) * scale);
        }
        int token = l >> 2, c = l & 3;
        v8h v0 = *(const v8h*)&tw_l[token * 72 + c * 16];
        v8h v1 = *(const v8h*)&tw_l[token * 72 + c * 16 + 8];
        _Float16* dp = dst + (size_t)(tok0 + token) * 64 + c * 16;
        *(v8h*)(dp) = v0;
        *(v8h*)(dp + 8) = v1;
    }
    {
        const _Float16* wp = wallT + 2 * 8192;
        int tokg = tok0 + lo;
        int bb = tokg >> 12, n = tokg & 4095;
        #pragma unroll
        for (int oc = 0; oc < 4; ++oc) {
            v4f acc = ZV4;
            #pragma unroll
            for (int kc = 0; kc < 4; ++kc) {
                v8h A = *(const v8h*)(wp + (oc * 16 + lo) * 128 + kc * 32 + h * 8);
                acc = MFMA16(A, xA[kc], acc);
            }
            #pragma unroll
            for (int rr = 0; rr < 4; ++rr) {
                int o = oc * 16 + 4 * h + rr;
                gT[((size_t)bb * 64 + o) * 4096 + n] = (_Float16)(acc[rr] + gb[o]);
            }
        }
    }
}

// ---------------------------------------------------------------- k_attn ----
// Flash attention, 32x32x16 MFMA, in-register P, DOUBLE-BUFFERED tiles with
// ONE barrier/iter (issue-early/write-late prefetch). Softmax in log2 domain
// (theta pre-scaled). Grid 512 (b=bid&7 XCD-partition), 8 waves = 2qt x 4kh.
__global__ __launch_bounds__(512, 4) void k_attn(
    const _Float16* __restrict__ theta,
    const _Float16* __restrict__ phi,
    const _Float16* __restrict__ gT,
    const _Float16* __restrict__ Wt,
    const float* __restrict__ sc, const float* __restrict__ bi,
    const float* __restrict__ x, float* __restrict__ out)
{
    __shared__ __align__(16) _Float16 ldsbuf[32768];     // 64KB: ph[2] | gv[2]
    __shared__ float zf[8 * 32];                         // 1KB: m + log2 l

    const int t = threadIdx.x;
    const int w = t >> 6, l = t & 63, q32 = l & 31, hi2 = l >> 5;
    const int qt = w & 1, kh = w >> 1;
    const int bid = blockIdx.x;
    const int b = bid & 7, qb = bid >> 3;
    const size_t tok0 = (size_t)b * 4096 + qb * 64;
    const int tokA = (int)(qb * 64) + qt * 32;

    char* phB = (char*)ldsbuf;                           // 2 x 16KB, TA64
    char* gvB = (char*)ldsbuf + 32768;                   // 2 x 16KB, TA128

    // theta B-frags (log2-scaled): col = q = q32, k = kc*16 + hi2*8 + j
    v8h thB[4];
    #pragma unroll
    for (int kc = 0; kc < 4; ++kc)
        thB[kc] = *(const v8h*)(theta +
            (tok0 + qt * 32 + q32) * 64 + kc * 16 + hi2 * 8);

    const _Float16* phb = phi + (size_t)b * 4096 * 64;
    const _Float16* gvb = gT + (size_t)b * 64 * 4096;

    v16f yacc[2];
    #pragma unroll
    for (int df = 0; df < 2; ++df)
        #pragma unroll
        for (int r = 0; r < 16; ++r) yacc[df][r] = 0.f;
    float mrow = -INFINITY, lpart = 0.f;

    // hoisted swizzled read offsets (within one 16KB buffer)
    int qkRd[4], gvRd[2][2];
    #pragma unroll
    for (int kc = 0; kc < 4; ++kc)
        qkRd[kc] = TA64(kh * 32 + q32, (kc * 16 + hi2 * 8) * 2);
    #pragma unroll
    for (int df = 0; df < 2; ++df)
        #pragma unroll
        for (int s = 0; s < 2; ++s)
            gvRd[df][s] = TA128(df * 32 + q32, (kh * 32 + s * 16 + hi2 * 8) * 2);

    // staging: ph 2 chunks/thread (rows t>>3, +64), gv 2 (rows t>>4, +32)
    const int phA0 = TA64(t >> 3, (t & 7) * 16);
    const int phA1 = TA64((t >> 3) + 64, (t & 7) * 16);
    const int gvA0 = TA128(t >> 4, (t & 15) * 16);
    const int gvA1 = TA128((t >> 4) + 32, (t & 15) * 16);
    const _Float16* pPh = phb + (size_t)(t >> 3) * 64 + (t & 7) * 8;
    const _Float16* pGv = gvb + (size_t)(t >> 4) * 4096 + (t & 15) * 8;

    // prefetch tile 0
    v8h pf0 = *(const v8h*)(pPh);
    v8h pf1 = *(const v8h*)(pPh + 64 * 64);
    v8h pf2 = *(const v8h*)(pGv);
    v8h pf3 = *(const v8h*)(pGv + (size_t)32 * 4096);
    pPh += 8192; pGv += 128;

    for (int kt = 0; kt < 32; ++kt) {
        char* phL = phB + (kt & 1) * 16384;
        char* gvL = gvB + (kt & 1) * 16384;
        // write tile kt (loaded last iter); safe: buf[kt&1] last read at kt-2,
        // all waves passed barrier of kt-1 since then.
        *(v8h*)(phL + phA0) = pf0;
        *(v8h*)(phL + phA1) = pf1;
        *(v8h*)(gvL + gvA0) = pf2;
        *(v8h*)(gvL + gvA1) = pf3;
        if (kt < 31) {                   // issue loads for tile kt+1 (async)
            pf0 = *(const v8h*)(pPh);
            pf1 = *(const v8h*)(pPh + 64 * 64);
            pf2 = *(const v8h*)(pGv);
            pf3 = *(const v8h*)(pGv + (size_t)32 * 4096);
            pPh += 8192; pGv += 128;
        }
        __syncthreads();                 // tile kt visible everywhere
        // ---- QK^T (log2 domain): S = logit(key kh*32+(r&3)+8*(r>>2)+4hi2, q32)
        v16f S;
        #pragma unroll
        for (int r = 0; r < 16; ++r) S[r] = 0.f;
        __builtin_amdgcn_s_setprio(1);
        #pragma unroll
        for (int kc = 0; kc < 4; ++kc) {
            v8h A = *(const v8h*)(phL + qkRd[kc]);
            S = MFMA32(A, thB[kc], S);
        }
        __builtin_amdgcn_s_setprio(0);
        // ---- softmax: max3-shaped tree + 1 shfl; defer-max THR = 8*log2e
        float m0 = fmaxf(fmaxf(S[0], S[1]), S[2]);
        float m1 = fmaxf(fmaxf(S[3], S[4]), S[5]);
        float m2 = fmaxf(fmaxf(S[6], S[7]), S[8]);
        float m3 = fmaxf(fmaxf(S[9], S[10]), S[11]);
        float m4 = fmaxf(fmaxf(S[12], S[13]), S[14]);
        float vmax = fmaxf(fmaxf(fmaxf(m0, m1), fmaxf(m2, m3)),
                           fmaxf(m4, S[15]));
        vmax = fmaxf(vmax, __shfl_xor(vmax, 32));
        if (!__all(vmax <= mrow + 11.54f)) {
            float mn = fmaxf(mrow, vmax);
            float aa = exp2f(mrow - mn);             // 0 on first tile
            mrow = mn;
            lpart *= aa;
            #pragma unroll
            for (int df = 0; df < 2; ++df)
                #pragma unroll
                for (int r = 0; r < 16; ++r)
                    yacc[df][r] *= aa;
        }
        float psum = 0.f;
        #pragma unroll
        for (int r = 0; r < 16; ++r) {
            S[r] = exp2f(S[r] - mrow);
            psum += S[r];
        }
        lpart += psum;
        // ---- P -> PV B-frags in-register (cvt_pk + permlane32_swap)
        unsigned int W0 = pk_f16(S[0], S[1]),   W1 = pk_f16(S[2], S[3]);
        unsigned int W2 = pk_f16(S[4], S[5]),   W3 = pk_f16(S[6], S[7]);
        unsigned int W4 = pk_f16(S[8], S[9]),   W5 = pk_f16(S[10], S[11]);
        unsigned int W6 = pk_f16(S[12], S[13]), W7 = pk_f16(S[14], S[15]);
        pl32swap(W0, W2); pl32swap(W1, W3);
        pl32swap(W4, W6); pl32swap(W5, W7);
        uint4 ub1; ub1.x = W0; ub1.y = W1; ub1.z = W2; ub1.w = W3;
        uint4 ub2; ub2.x = W4; ub2.y = W5; ub2.z = W6; ub2.w = W7;
        v8h pBv[2] = {__builtin_bit_cast(v8h, ub1), __builtin_bit_cast(v8h, ub2)};
        // ---- PV
        __builtin_amdgcn_s_setprio(1);
        #pragma unroll
        for (int df = 0; df < 2; ++df)
            #pragma unroll
            for (int s = 0; s < 2; ++s) {
                v8h A = *(const v8h*)(gvL + gvRd[df][s]);
                yacc[df] = MFMA32(A, pBv[s], yacc[df]);
            }
        __builtin_amdgcn_s_setprio(0);
    }

    __syncthreads();                     // all tile reads done; reuse ph bufs
    // ---- write partials: u = y/l (fp16) to slot w; z = m + log2 l
    float lrow = lpart + __shfl_xor(lpart, 32);
    float inv = 1.0f / lrow;
    {
        char* slot = (char*)ldsbuf + w * 4096 + l * 64;
        #pragma unroll
        for (int j = 0; j < 4; ++j) {
            int df = j >> 1, r0 = (j & 1) * 8;
            uint4 u;
            u.x = pk_f16(yacc[df][r0 + 0] * inv, yacc[df][r0 + 1] * inv);
            u.y = pk_f16(yacc[df][r0 + 2] * inv, yacc[df][r0 + 3] * inv);
            u.z = pk_f16(yacc[df][r0 + 4] * inv, yacc[df][r0 + 5] * inv);
            u.w = pk_f16(yacc[df][r0 + 6] * inv, yacc[df][r0 + 7] * inv);
            *(uint4*)(slot + (j * 16 ^ ((l & 3) << 4))) = u;
        }
        zf[w * 32 + q32] = mrow + __log2f(lrow);
    }
    __syncthreads();
    if (w >= 2) return;

    // ---- combine 4 kh partials (slots kp*2 + qt; this wave: qt = w)
    float zq[4];
    #pragma unroll
    for (int kp = 0; kp < 4; ++kp) zq[kp] = zf[(kp * 2 + qt) * 32 + q32];
    float zmx = fmaxf(fmaxf(zq[0], zq[1]), fmaxf(zq[2], zq[3]));
    float wsum = 0.f;
    float yfin[2][16];
    #pragma unroll
    for (int df = 0; df < 2; ++df)
        #pragma unroll
        for (int r = 0; r < 16; ++r) yfin[df][r] = 0.f;
    #pragma unroll
    for (int kp = 0; kp < 4; ++kp) {
        char* slot = (char*)ldsbuf + (kp * 2 + qt) * 4096 + l * 64;
        float wk = exp2f(zq[kp] - zmx);
        wsum += wk;
        #pragma unroll
        for (int j = 0; j < 4; ++j) {
            v8h c = *(const v8h*)(slot + (j * 16 ^ ((l & 3) << 4)));
            int df = j >> 1, r0 = (j & 1) * 8;
            #pragma unroll
            for (int e = 0; e < 8; ++e)
                yfin[df][r0 + e] += wk * (float)c[e];
        }
    }
    float nrm = 1.0f / wsum;
    // ---- epilogue A-frags: y rows q, k = d
    v8h yA[4];
    #pragma unroll
    for (int kc = 0; kc < 4; ++kc) {
        int df = kc >> 1, r0 = (kc & 1) * 8;
        unsigned int Wa = pk_f16(yfin[df][r0 + 0] * nrm, yfin[df][r0 + 1] * nrm);
        unsigned int Wb2 = pk_f16(yfin[df][r0 + 2] * nrm, yfin[df][r0 + 3] * nrm);
        unsigned int Wc = pk_f16(yfin[df][r0 + 4] * nrm, yfin[df][r0 + 5] * nrm);
        unsigned int Wd = pk_f16(yfin[df][r0 + 6] * nrm, yfin[df][r0 + 7] * nrm);
        pl32swap(Wa, Wc); pl32swap(Wb2, Wd);
        uint4 u; u.x = Wa; u.y = Wb2; u.z = Wc; u.w = Wd;
        yA[kc] = __builtin_bit_cast(v8h, u);
    }
    // ---- wy = y @ W -> BN + residual
    const float* xb = x + (size_t)b * 4096 * 128;
    float* ob = out + (size_t)b * 4096 * 128;
    #pragma unroll
    for (int cf = 0; cf < 4; ++cf) {
        int c = cf * 32 + q32;
        v16f wy;
        #pragma unroll
        for (int r = 0; r < 16; ++r) wy[r] = 0.f;
        #pragma unroll
        for (int kc = 0; kc < 4; ++kc) {
            v8h wB = *(const v8h*)(Wt + c * 64 + kc * 16 + hi2 * 8);
            wy = MFMA32(yA[kc], wB, wy);
        }
        float scc = sc[c], bic = bi[c];
        #pragma unroll
        for (int r = 0; r < 16; ++r) {
            int qrow = (r & 3) + 8 * (r >> 2) + 4 * hi2;
            size_t off = (size_t)(tokA + qrow) * 128 + c;
            ob[off] = wy[r] * scc + bic + xb[off];
        }
    }
}

// ------------------------------------------------------------------ launch --
extern "C" void kernel_launch(void* const* d_in, const int* in_sizes, int n_in,
                              void* d_out, int out_size, void* d_ws, size_t ws_size,
                              hipStream_t stream) {
    const float* x     = (const float*)d_in[0];
    const float* tw    = (const float*)d_in[1];
    const float* tb    = (const float*)d_in[2];
    const float* pw    = (const float*)d_in[3];
    const float* pb    = (const float*)d_in[4];
    const float* gw    = (const float*)d_in[5];
    const float* gb    = (const float*)d_in[6];
    const float* Ww    = (const float*)d_in[7];
    const float* Wb    = (const float*)d_in[8];
    const float* gamma = (const float*)d_in[9];
    const float* beta  = (const float*)d_in[10];
    const float* mean  = (const float*)d_in[11];
    const float* var   = (const float*)d_in[12];

    char* ws = (char*)d_ws;
    _Float16* theta = (_Float16*)ws;                       // 4 MB (log2-scaled)
    _Float16* phi   = (_Float16*)(ws + (4u << 20));        // 4 MB
    _Float16* gT    = (_Float16*)(ws + (8u << 20));        // 4 MB
    _Float16* Wt    = (_Float16*)(ws + (12u << 20));       // 16 KB
    _Float16* wallT = (_Float16*)(ws + (12u << 20) + (1u << 16));  // 48 KB
    float* sc       = (float*)(ws + (12u << 20) + (2u << 16));
    float* bi       = sc + 128;

    k_prep<<<16, 256, 0, stream>>>(tw, pw, gw, Ww, Wb, gamma, beta, mean, var,
                                   Wt, wallT, sc, bi);
    k_proj<<<256, 512, 0, stream>>>(x, wallT, tb, pb, gb, theta, phi, gT);
    k_attn<<<512, 512, 0, stream>>>(theta, phi, gT, Wt, sc, bi,
                                    x, (float*)d_out);
}

// Round 13
// 100.332 us; speedup vs baseline: 1.0963x; 1.0963x over previous
//
#include <hip/hip_runtime.h>
#include <math.h>

typedef _Float16 v8h __attribute__((ext_vector_type(8)));
typedef float v4f __attribute__((ext_vector_type(4)));
typedef float v16f __attribute__((ext_vector_type(16)));

#define MFMA32(a, b, c) __builtin_amdgcn_mfma_f32_32x32x16_f16((a), (b), (c), 0, 0, 0)
#define MFMA16(a, b, c) __builtin_amdgcn_mfma_f32_16x16x32_f16((a), (b), (c), 0, 0, 0)
#define ZV4 ((v4f){0.f, 0.f, 0.f, 0.f})
#define LOG2E 1.44269504f

// swizzled tile addressing (byte offsets)
#define TA64(row, colb)  ((((row) * 128) + (colb)) ^ (((row) & 7) << 4))
#define TA128(row, colb) ((((row) * 256) + (colb)) ^ (((row) & 15) << 4))

// raw barrier: waves' LDS writes visible, but global loads STAY IN FLIGHT
// (HIP __syncthreads would emit s_waitcnt vmcnt(0) and drain the prefetch)
#define RAW_BARRIER() do {                                        \
    asm volatile("s_waitcnt lgkmcnt(0)" ::: "memory");            \
    asm volatile("s_barrier" ::: "memory");                       \
} while (0)

__device__ __forceinline__ unsigned int pk_f16(float a, float b) {
    return __builtin_bit_cast(unsigned int, __builtin_amdgcn_cvt_pkrtz(a, b));
}
__device__ __forceinline__ void pl32swap(unsigned int& a, unsigned int& b) {
    asm("v_permlane32_swap_b32 %0, %1" : "+v"(a), "+v"(b));
}
__device__ __forceinline__ float fexp2(float x) {   // bare v_exp_f32 (2^x)
    float r;
    asm("v_exp_f32 %0, %1" : "=v"(r) : "v"(x));
    return r;
}

// ---------------------------------------------------------------- k_prep ----
__global__ __launch_bounds__(256) void k_prep(
    const float* __restrict__ tw, const float* __restrict__ pw,
    const float* __restrict__ gw,
    const float* __restrict__ Ww, const float* __restrict__ Wb,
    const float* __restrict__ gamma, const float* __restrict__ beta,
    const float* __restrict__ mean, const float* __restrict__ var,
    _Float16* __restrict__ Wt, _Float16* __restrict__ wallT,
    float* __restrict__ sc, float* __restrict__ bi)
{
    int gid = blockIdx.x * 256 + threadIdx.x;    // 4096 threads
    #pragma unroll
    for (int r = 0; r < 2; ++r) {
        int idx = r * 4096 + gid;                // 8192 = 64*128
        int d = idx >> 7, c = idx & 127;
        Wt[c * 64 + d] = (_Float16)Ww[idx];      // Wt[c][d] = W_w[d][c]
    }
    #pragma unroll
    for (int r = 0; r < 6; ++r) {
        int idx = r * 4096 + gid;                // 24576 = 3*64*128
        int p = idx >> 13, rem = idx & 8191;
        int o = rem >> 7, k = rem & 127;
        const float* wm = (p == 0) ? tw : (p == 1) ? pw : gw;
        wallT[idx] = (_Float16)wm[k * 64 + o];
    }
    if (blockIdx.x == 0 && threadIdx.x < 128) {
        int c = threadIdx.x;
        float inv = gamma[c] * rsqrtf(var[c] + 1e-4f);
        sc[c] = inv;
        bi[c] = (Wb[c] - mean[c]) * inv + beta[c];
    }
}

// ---------------------------------------------------------------- k_proj ----
// fp16 MFMA projections, no barriers. theta PRE-SCALED by log2(e) so the
// attention softmax can use v_exp_f32 (2^x) directly.
__global__ __launch_bounds__(512, 4) void k_proj(
    const float* __restrict__ x, const _Float16* __restrict__ wallT,
    const float* __restrict__ tb, const float* __restrict__ pb,
    const float* __restrict__ gb,
    _Float16* __restrict__ theta, _Float16* __restrict__ phi,
    _Float16* __restrict__ gT)
{
    __shared__ __align__(16) _Float16 tsc[8][16 * 72];
    const int t = threadIdx.x;
    const int w = t >> 6, l = t & 63, h = l >> 4, lo = l & 15;
    const int tok0 = blockIdx.x * 128 + w * 16;
    _Float16* tw_l = &tsc[w][0];

    v8h xA[4];
    #pragma unroll
    for (int kc = 0; kc < 4; ++kc) {
        const float* px = x + (size_t)(tok0 + lo) * 128 + kc * 32 + h * 8;
        float4 f0 = *(const float4*)(px);
        float4 f1 = *(const float4*)(px + 4);
        uint4 u;
        u.x = pk_f16(f0.x, f0.y); u.y = pk_f16(f0.z, f0.w);
        u.z = pk_f16(f1.x, f1.y); u.w = pk_f16(f1.z, f1.w);
        xA[kc] = __builtin_bit_cast(v8h, u);
    }

    #pragma unroll
    for (int p = 0; p < 2; ++p) {                // theta, phi
        const _Float16* wp = wallT + p * 8192;
        const float* bias = (p == 0) ? tb : pb;
        _Float16* dst = (p == 0) ? theta : phi;
        const float scale = (p == 0) ? LOG2E : 1.0f;
        #pragma unroll
        for (int oc = 0; oc < 4; ++oc) {
            int o = oc * 16 + lo;
            v4f acc = ZV4;
            #pragma unroll
            for (int kc = 0; kc < 4; ++kc) {
                v8h B = *(const v8h*)(wp + o * 128 + kc * 32 + h * 8);
                acc = MFMA16(xA[kc], B, acc);
            }
            float bv = bias[o];
            #pragma unroll
            for (int rr = 0; rr < 4; ++rr)
                tw_l[(4 * h + rr) * 72 + o] = (_Float16)((acc[rr] + bv) * scale);
        }
        int token = l >> 2, c = l & 3;
        v8h v0 = *(const v8h*)&tw_l[token * 72 + c * 16];
        v8h v1 = *(const v8h*)&tw_l[token * 72 + c * 16 + 8];
        _Float16* dp = dst + (size_t)(tok0 + token) * 64 + c * 16;
        *(v8h*)(dp) = v0;
        *(v8h*)(dp + 8) = v1;
    }
    {
        const _Float16* wp = wallT + 2 * 8192;
        int tokg = tok0 + lo;
        int bb = tokg >> 12, n = tokg & 4095;
        #pragma unroll
        for (int oc = 0; oc < 4; ++oc) {
            v4f acc = ZV4;
            #pragma unroll
            for (int kc = 0; kc < 4; ++kc) {
                v8h A = *(const v8h*)(wp + (oc * 16 + lo) * 128 + kc * 32 + h * 8);
                acc = MFMA16(A, xA[kc], acc);
            }
            #pragma unroll
            for (int rr = 0; rr < 4; ++rr) {
                int o = oc * 16 + 4 * h + rr;
                gT[((size_t)bb * 64 + o) * 4096 + n] = (_Float16)(acc[rr] + gb[o]);
            }
        }
    }
}

// ---------------------------------------------------------------- k_attn ----
// Flash attention, 32x32x16 MFMA, in-register P, double-buffered tiles with
// ONE RAW barrier/iter — prefetch global loads stay in flight across it
// (T3/T4). Softmax in log2 domain with bare v_exp_f32. Grid 512 (b=bid&7
// XCD-partition), 8 waves = 2qt x 4kh.
__global__ __launch_bounds__(512, 4) void k_attn(
    const _Float16* __restrict__ theta,
    const _Float16* __restrict__ phi,
    const _Float16* __restrict__ gT,
    const _Float16* __restrict__ Wt,
    const float* __restrict__ sc, const float* __restrict__ bi,
    const float* __restrict__ x, float* __restrict__ out)
{
    __shared__ __align__(16) _Float16 ldsbuf[32768];     // 64KB: ph[2] | gv[2]
    __shared__ float zf[8 * 32];                         // 1KB: m + log2 l

    const int t = threadIdx.x;
    const int w = t >> 6, l = t & 63, q32 = l & 31, hi2 = l >> 5;
    const int qt = w & 1, kh = w >> 1;
    const int bid = blockIdx.x;
    const int b = bid & 7, qb = bid >> 3;
    const size_t tok0 = (size_t)b * 4096 + qb * 64;
    const int tokA = (int)(qb * 64) + qt * 32;

    char* phB = (char*)ldsbuf;                           // 2 x 16KB, TA64
    char* gvB = (char*)ldsbuf + 32768;                   // 2 x 16KB, TA128

    // theta B-frags (log2-scaled): col = q = q32, k = kc*16 + hi2*8 + j
    v8h thB[4];
    #pragma unroll
    for (int kc = 0; kc < 4; ++kc)
        thB[kc] = *(const v8h*)(theta +
            (tok0 + qt * 32 + q32) * 64 + kc * 16 + hi2 * 8);

    const _Float16* phb = phi + (size_t)b * 4096 * 64;
    const _Float16* gvb = gT + (size_t)b * 64 * 4096;

    v16f yacc[2];
    #pragma unroll
    for (int df = 0; df < 2; ++df)
        #pragma unroll
        for (int r = 0; r < 16; ++r) yacc[df][r] = 0.f;
    float mrow = -INFINITY, lpart = 0.f;

    // hoisted swizzled read offsets (within one 16KB buffer)
    int qkRd[4], gvRd[2][2];
    #pragma unroll
    for (int kc = 0; kc < 4; ++kc)
        qkRd[kc] = TA64(kh * 32 + q32, (kc * 16 + hi2 * 8) * 2);
    #pragma unroll
    for (int df = 0; df < 2; ++df)
        #pragma unroll
        for (int s = 0; s < 2; ++s)
            gvRd[df][s] = TA128(df * 32 + q32, (kh * 32 + s * 16 + hi2 * 8) * 2);

    // staging: ph 2 chunks/thread (rows t>>3, +64), gv 2 (rows t>>4, +32)
    const int phA0 = TA64(t >> 3, (t & 7) * 16);
    const int phA1 = TA64((t >> 3) + 64, (t & 7) * 16);
    const int gvA0 = TA128(t >> 4, (t & 15) * 16);
    const int gvA1 = TA128((t >> 4) + 32, (t & 15) * 16);
    const _Float16* pPh = phb + (size_t)(t >> 3) * 64 + (t & 7) * 8;
    const _Float16* pGv = gvb + (size_t)(t >> 4) * 4096 + (t & 15) * 8;

    // prefetch tile 0
    v8h pf0 = *(const v8h*)(pPh);
    v8h pf1 = *(const v8h*)(pPh + 64 * 64);
    v8h pf2 = *(const v8h*)(pGv);
    v8h pf3 = *(const v8h*)(pGv + (size_t)32 * 4096);
    pPh += 8192; pGv += 128;

    for (int kt = 0; kt < 32; ++kt) {
        char* phL = phB + (kt & 1) * 16384;
        char* gvL = gvB + (kt & 1) * 16384;
        // write tile kt (compiler inserts counted vmcnt for pf deps);
        // safe vs readers: buf[kt&1] last read at kt-2, all waves passed
        // barrier kt-1 since.
        *(v8h*)(phL + phA0) = pf0;
        *(v8h*)(phL + phA1) = pf1;
        *(v8h*)(gvL + gvA0) = pf2;
        *(v8h*)(gvL + gvA1) = pf3;
        if (kt < 31) {                   // issue loads for tile kt+1; they
            pf0 = *(const v8h*)(pPh);    // stay in flight across RAW_BARRIER
            pf1 = *(const v8h*)(pPh + 64 * 64);
            pf2 = *(const v8h*)(pGv);
            pf3 = *(const v8h*)(pGv + (size_t)32 * 4096);
            pPh += 8192; pGv += 128;
        }
        RAW_BARRIER();                   // LDS writes visible; vmem NOT drained
        // ---- QK^T (log2 domain): S = logit(key kh*32+(r&3)+8*(r>>2)+4hi2, q32)
        v16f S;
        #pragma unroll
        for (int r = 0; r < 16; ++r) S[r] = 0.f;
        __builtin_amdgcn_s_setprio(1);
        #pragma unroll
        for (int kc = 0; kc < 4; ++kc) {
            v8h A = *(const v8h*)(phL + qkRd[kc]);
            S = MFMA32(A, thB[kc], S);
        }
        __builtin_amdgcn_s_setprio(0);
        // ---- softmax: max tree + 1 shfl; defer-max THR = 8*log2e
        float m0 = fmaxf(fmaxf(S[0], S[1]), S[2]);
        float m1 = fmaxf(fmaxf(S[3], S[4]), S[5]);
        float m2 = fmaxf(fmaxf(S[6], S[7]), S[8]);
        float m3 = fmaxf(fmaxf(S[9], S[10]), S[11]);
        float m4 = fmaxf(fmaxf(S[12], S[13]), S[14]);
        float vmax = fmaxf(fmaxf(fmaxf(m0, m1), fmaxf(m2, m3)),
                           fmaxf(m4, S[15]));
        vmax = fmaxf(vmax, __shfl_xor(vmax, 32));
        if (!__all(vmax <= mrow + 11.54f)) {
            float mn = fmaxf(mrow, vmax);
            float aa = fexp2(mrow - mn);             // 0 on first tile
            mrow = mn;
            lpart *= aa;
            #pragma unroll
            for (int df = 0; df < 2; ++df)
                #pragma unroll
                for (int r = 0; r < 16; ++r)
                    yacc[df][r] *= aa;
        }
        float psum = 0.f;
        #pragma unroll
        for (int r = 0; r < 16; ++r) {
            S[r] = fexp2(S[r] - mrow);
            psum += S[r];
        }
        lpart += psum;
        // ---- P -> PV B-frags in-register (cvt_pk + permlane32_swap)
        unsigned int W0 = pk_f16(S[0], S[1]),   W1 = pk_f16(S[2], S[3]);
        unsigned int W2 = pk_f16(S[4], S[5]),   W3 = pk_f16(S[6], S[7]);
        unsigned int W4 = pk_f16(S[8], S[9]),   W5 = pk_f16(S[10], S[11]);
        unsigned int W6 = pk_f16(S[12], S[13]), W7 = pk_f16(S[14], S[15]);
        pl32swap(W0, W2); pl32swap(W1, W3);
        pl32swap(W4, W6); pl32swap(W5, W7);
        uint4 ub1; ub1.x = W0; ub1.y = W1; ub1.z = W2; ub1.w = W3;
        uint4 ub2; ub2.x = W4; ub2.y = W5; ub2.z = W6; ub2.w = W7;
        v8h pBv[2] = {__builtin_bit_cast(v8h, ub1), __builtin_bit_cast(v8h, ub2)};
        // ---- PV
        __builtin_amdgcn_s_setprio(1);
        #pragma unroll
        for (int df = 0; df < 2; ++df)
            #pragma unroll
            for (int s = 0; s < 2; ++s) {
                v8h A = *(const v8h*)(gvL + gvRd[df][s]);
                yacc[df] = MFMA32(A, pBv[s], yacc[df]);
            }
        __builtin_amdgcn_s_setprio(0);
    }

    __syncthreads();                     // all tile reads done; reuse ph bufs
    // ---- write partials: u = y/l (fp16) to slot w; z = m + log2 l
    float lrow = lpart + __shfl_xor(lpart, 32);
    float inv = 1.0f / lrow;
    {
        char* slot = (char*)ldsbuf + w * 4096 + l * 64;
        #pragma unroll
        for (int j = 0; j < 4; ++j) {
            int df = j >> 1, r0 = (j & 1) * 8;
            uint4 u;
            u.x = pk_f16(yacc[df][r0 + 0] * inv, yacc[df][r0 + 1] * inv);
            u.y = pk_f16(yacc[df][r0 + 2] * inv, yacc[df][r0 + 3] * inv);
            u.z = pk_f16(yacc[df][r0 + 4] * inv, yacc[df][r0 + 5] * inv);
            u.w = pk_f16(yacc[df][r0 + 6] * inv, yacc[df][r0 + 7] * inv);
            *(uint4*)(slot + (j * 16 ^ ((l & 3) << 4))) = u;
        }
        zf[w * 32 + q32] = mrow + __log2f(lrow);
    }
    __syncthreads();
    if (w >= 2) return;

    // ---- combine 4 kh partials (slots kp*2 + qt; this wave: qt = w)
    float zq[4];
    #pragma unroll
    for (int kp = 0; kp < 4; ++kp) zq[kp] = zf[(kp * 2 + qt) * 32 + q32];
    float zmx = fmaxf(fmaxf(zq[0], zq[1]), fmaxf(zq[2], zq[3]));
    float wsum = 0.f;
    float yfin[2][16];
    #pragma unroll
    for (int df = 0; df < 2; ++df)
        #pragma unroll
        for (int r = 0; r < 16; ++r) yfin[df][r] = 0.f;
    #pragma unroll
    for (int kp = 0; kp < 4; ++kp) {
        char* slot = (char*)ldsbuf + (kp * 2 + qt) * 4096 + l * 64;
        float wk = fexp2(zq[kp] - zmx);
        wsum += wk;
        #pragma unroll
        for (int j = 0; j < 4; ++j) {
            v8h c = *(const v8h*)(slot + (j * 16 ^ ((l & 3) << 4)));
            int df = j >> 1, r0 = (j & 1) * 8;
            #pragma unroll
            for (int e = 0; e < 8; ++e)
                yfin[df][r0 + e] += wk * (float)c[e];
        }
    }
    float nrm = 1.0f / wsum;
    // ---- epilogue A-frags: y rows q, k = d
    v8h yA[4];
    #pragma unroll
    for (int kc = 0; kc < 4; ++kc) {
        int df = kc >> 1, r0 = (kc & 1) * 8;
        unsigned int Wa = pk_f16(yfin[df][r0 + 0] * nrm, yfin[df][r0 + 1] * nrm);
        unsigned int Wb2 = pk_f16(yfin[df][r0 + 2] * nrm, yfin[df][r0 + 3] * nrm);
        unsigned int Wc = pk_f16(yfin[df][r0 + 4] * nrm, yfin[df][r0 + 5] * nrm);
        unsigned int Wd = pk_f16(yfin[df][r0 + 6] * nrm, yfin[df][r0 + 7] * nrm);
        pl32swap(Wa, Wc); pl32swap(Wb2, Wd);
        uint4 u; u.x = Wa; u.y = Wb2; u.z = Wc; u.w = Wd;
        yA[kc] = __builtin_bit_cast(v8h, u);
    }
    // ---- wy = y @ W -> BN + residual
    const float* xb = x + (size_t)b * 4096 * 128;
    float* ob = out + (size_t)b * 4096 * 128;
    #pragma unroll
    for (int cf = 0; cf < 4; ++cf) {
        int c = cf * 32 + q32;
        v16f wy;
        #pragma unroll
        for (int r = 0; r < 16; ++r) wy[r] = 0.f;
        #pragma unroll
        for (int kc = 0; kc < 4; ++kc) {
            v8h wB = *(const v8h*)(Wt + c * 64 + kc * 16 + hi2 * 8);
            wy = MFMA32(yA[kc], wB, wy);
        }
        float scc = sc[c], bic = bi[c];
        #pragma unroll
        for (int r = 0; r < 16; ++r) {
            int qrow = (r & 3) + 8 * (r >> 2) + 4 * hi2;
            size_t off = (size_t)(tokA + qrow) * 128 + c;
            ob[off] = wy[r] * scc + bic + xb[off];
        }
    }
}

// ------------------------------------------------------------------ launch --
extern "C" void kernel_launch(void* const* d_in, const int* in_sizes, int n_in,
                              void* d_out, int out_size, void* d_ws, size_t ws_size,
                              hipStream_t stream) {
    const float* x     = (const float*)d_in[0];
    const float* tw    = (const float*)d_in[1];
    const float* tb    = (const float*)d_in[2];
    const float* pw    = (const float*)d_in[3];
    const float* pb    = (const float*)d_in[4];
    const float* gw    = (const float*)d_in[5];
    const float* gb    = (const float*)d_in[6];
    const float* Ww    = (const float*)d_in[7];
    const float* Wb    = (const float*)d_in[8];
    const float* gamma = (const float*)d_in[9];
    const float* beta  = (const float*)d_in[10];
    const float* mean  = (const float*)d_in[11];
    const float* var   = (const float*)d_in[12];

    char* ws = (char*)d_ws;
    _Float16* theta = (_Float16*)ws;                       // 4 MB (log2-scaled)
    _Float16* phi   = (_Float16*)(ws + (4u << 20));        // 4 MB
    _Float16* gT    = (_Float16*)(ws + (8u << 20));        // 4 MB
    _Float16* Wt    = (_Float16*)(ws + (12u << 20));       // 16 KB
    _Float16* wallT = (_Float16*)(ws + (12u << 20) + (1u << 16));  // 48 KB
    float* sc       = (float*)(ws + (12u << 20) + (2u << 16));
    float* bi       = sc + 128;

    k_prep<<<16, 256, 0, stream>>>(tw, pw, gw, Ww, Wb, gamma, beta, mean, var,
                                   Wt, wallT, sc, bi);
    k_proj<<<256, 512, 0, stream>>>(x, wallT, tb, pb, gb, theta, phi, gT);
    k_attn<<<512, 512, 0, stream>>>(theta, phi, gT, Wt, sc, bi,
                                    x, (float*)d_out);
}